// Round 17
// baseline (345.877 us; speedup 1.0000x reference)
//
#include <hip/hip_runtime.h>
#include <hip/hip_bf16.h>

typedef __attribute__((ext_vector_type(8))) short bf16x8;
typedef __attribute__((ext_vector_type(4))) float f32x4;

__device__ inline ushort f2bf(float f) {
    uint u = __float_as_uint(f);
    u += 0x7fff + ((u >> 16) & 1);
    return (ushort)(u >> 16);
}
__device__ inline float bf2f(ushort h) {
    return __uint_as_float(((uint)h) << 16);
}

__device__ inline void gload16(const void* g, void* lds) {
    __builtin_amdgcn_global_load_lds(
        (const __attribute__((address_space(1))) void*)g,
        (__attribute__((address_space(3))) void*)lds, 16, 0, 0);
}

// ---------------- merged prep: src->bf16, 6 weight transpose-converts, bias concat ----------------
__global__ __launch_bounds__(256) void prep(
    const float* __restrict__ src, ushort* __restrict__ src16,
    const float* __restrict__ Wq, const float* __restrict__ Wk,
    const float* __restrict__ Wv, const float* __restrict__ Wo,
    const float* __restrict__ W1, const float* __restrict__ W2,
    ushort* __restrict__ wqkv, ushort* __restrict__ wot,
    ushort* __restrict__ w1t, ushort* __restrict__ w2t,
    const float* __restrict__ bq, const float* __restrict__ bk,
    const float* __restrict__ bv, float* __restrict__ bqkv) {
    __shared__ float tile[32][33];
    int bid = blockIdx.x;
    const int t = threadIdx.x;
    if (bid < 16384) {
        int i = bid * 256 + t;
        float4 a = ((const float4*)src)[i];
        ushort4 o;
        o.x = f2bf(a.x); o.y = f2bf(a.y); o.z = f2bf(a.z); o.w = f2bf(a.w);
        ((ushort4*)src16)[i] = o;
        return;
    }
    bid -= 16384;
    const float* in; ushort* out; int Kd, Nd;
    if (bid < 1024) {
        int m = bid >> 8;
        in = (m == 0) ? Wq : (m == 1) ? Wk : (m == 2) ? Wv : Wo;
        out = (m == 3) ? wot : (wqkv + m * 512 * 512);
        Kd = 512; Nd = 512; bid &= 255;
    } else if (bid < 2048) { in = W1; out = w1t; Kd = 512; Nd = 2048; bid -= 1024; }
    else if (bid < 3072) { in = W2; out = w2t; Kd = 2048; Nd = 512; bid -= 2048; }
    else {
        int i = (bid - 3072) * 256 + t;
        if (i < 512) bqkv[i] = bq[i];
        else if (i < 1024) bqkv[i] = bk[i - 512];
        else if (i < 1536) bqkv[i] = bv[i - 1024];
        return;
    }
    const int nx = Nd / 32;
    const int nbase = (bid % nx) * 32, kb = (bid / nx) * 32;
    const int tx = t & 31, ty = t >> 5;
#pragma unroll
    for (int i = 0; i < 4; i++)
        tile[ty + i * 8][tx] = in[(size_t)(kb + ty + i * 8) * Nd + nbase + tx];
    __syncthreads();
#pragma unroll
    for (int i = 0; i < 4; i++) {
        int n = nbase + ty + i * 8, k = kb + tx;
        out[(size_t)n * Kd + k] = f2bf(tile[tx][ty + i * 8]);
    }
}

// ============ 256x256 persistent GEMM: BK=64, 2x64KB dbuf, ONE barrier per K-tile ============
// (r12-proven; see round-12 comments for the full sync/WAR/swizzle argument.)
// EPI: 2 = relu bf16; 4 = fused QKV (seg<2: elu+1) -> [3][M][512]
template <int EPI, int NT, int GB>
__global__ __launch_bounds__(512, 2) void gemm256(
    const ushort* __restrict__ A, const ushort* __restrict__ Bt,
    const float* __restrict__ bias, const ushort* __restrict__ res16,
    ushort* __restrict__ out16, int M, int N, int K, int nb1) {
    extern __shared__ char smem[];  // 2 * 65536
    const int t = threadIdx.x;
    const int w = t >> 6, l = t & 63;
    const int wr = w >> 2, wc = w & 3;
    const int nwg = gridDim.x, cpx = nwg >> 3;
    const int swz = (blockIdx.x & 7) * cpx + (blockIdx.x >> 3);
    int bx0, by0;
    if (GB == 0) { bx0 = (swz % nb1) * NT; by0 = swz / nb1; }
    else         { bx0 = swz % nb1;        by0 = (swz / nb1) * NT; }

    const int scoff = ((t & 7) ^ ((t >> 3) & 7)) * 8;
    const ushort* pA = A + (size_t)(by0 * 256 + (t >> 3)) * K + scoff;
    const ushort* pB = Bt + (size_t)(bx0 * 256 + (t >> 3)) * K + scoff;
    const size_t u64K = (size_t)64 * K;

    const int Kt = K >> 6;  // BK=64
    const int TOT = NT * Kt;
    int skt = 0;
    size_t adv = 0;

#define STG8(buf)                                                              \
    {                                                                          \
        char* Lb = (buf) + (w << 10);                                          \
        _Pragma("unroll")                                                      \
        for (int u = 0; u < 4; ++u) {                                          \
            gload16(pA + (size_t)u * u64K + (GB ? adv : 0) + skt * 64,         \
                    Lb + u * 8192);                                            \
            gload16(pB + (size_t)u * u64K + (GB ? 0 : adv) + skt * 64,         \
                    Lb + 32768 + u * 8192);                                    \
        }                                                                      \
        if (++skt == Kt) { skt = 0; adv += (size_t)256 * K; }                  \
    }

    const int cA0 = ((l >> 4) ^ (l & 7)) * 16;
    const int cA1 = ((4 + (l >> 4)) ^ (l & 7)) * 16;
    const int baseA = (wr * 128 + (l & 15)) * 128;
    const int baseB = 32768 + (wc * 64 + (l & 15)) * 128;

    STG8(smem);

    f32x4 acc[8][4] = {};
    int g = 0;
    for (int j = 0; j < NT; ++j) {
#pragma unroll 1
        for (int kt = 0; kt < Kt; ++kt, ++g) {
            asm volatile("s_waitcnt vmcnt(0)" ::: "memory");
            __builtin_amdgcn_s_barrier();
            __builtin_amdgcn_sched_barrier(0);

            const char* cb = smem + (g & 1) * 65536;
            if (g + 1 < TOT) STG8(smem + ((g + 1) & 1) * 65536);

            bf16x8 a[8], b[4];
#pragma unroll
            for (int n = 0; n < 4; n++) b[n] = *(const bf16x8*)(cb + baseB + n * 2048 + cA0);
#pragma unroll
            for (int m = 0; m < 8; m++) a[m] = *(const bf16x8*)(cb + baseA + m * 2048 + cA0);
#pragma unroll
            for (int m = 0; m < 8; m++)
#pragma unroll
                for (int n = 0; n < 4; n++)
                    acc[m][n] = __builtin_amdgcn_mfma_f32_16x16x32_bf16(a[m], b[n], acc[m][n], 0, 0, 0);
#pragma unroll
            for (int n = 0; n < 4; n++) b[n] = *(const bf16x8*)(cb + baseB + n * 2048 + cA1);
#pragma unroll
            for (int m = 0; m < 8; m++) a[m] = *(const bf16x8*)(cb + baseA + m * 2048 + cA1);
#pragma unroll
            for (int m = 0; m < 8; m++)
#pragma unroll
                for (int n = 0; n < 4; n++)
                    acc[m][n] = __builtin_amdgcn_mfma_f32_16x16x32_bf16(a[m], b[n], acc[m][n], 0, 0, 0);
        }

        {
            const int bx = (GB == 0) ? (bx0 + j) : bx0;
            const int by = (GB == 0) ? by0 : (by0 + j);
            const int row0 = by * 256 + wr * 128 + ((l >> 4) << 2);
            const int col0 = bx * 256 + wc * 64 + (l & 15);
            const int seg = bx >> 1;
            const size_t segoff = (size_t)seg * M * 512;
            const int c511 = col0 & 511;
            float bv[4];
#pragma unroll
            for (int n = 0; n < 4; n++) bv[n] = bias[col0 + n * 16];
#pragma unroll
            for (int m = 0; m < 8; m++) {
#pragma unroll
                for (int r = 0; r < 4; r++) {
                    const int row = row0 + m * 16 + r;
                    const size_t base = (size_t)row * N + col0;
#pragma unroll
                    for (int n = 0; n < 4; n++) {
                        float vv = acc[m][n][r] + bv[n];
                        if constexpr (EPI == 2) {
                            vv = vv > 0.f ? vv : 0.f;
                            out16[base + n * 16] = f2bf(vv);
                        } else if constexpr (EPI == 4) {
                            if (seg < 2) vv = vv > 0.f ? vv + 1.f : __expf(vv);
                            out16[segoff + (size_t)row * 512 + c511 + n * 16] = f2bf(vv);
                        } else {
                            out16[base + n * 16] = f2bf(vv);
                        }
                    }
                }
            }
            if (j + 1 < NT) {
#pragma unroll
                for (int m = 0; m < 8; m++)
#pragma unroll
                    for (int n = 0; n < 4; n++)
                        acc[m][n] = (f32x4){0.f, 0.f, 0.f, 0.f};
            }
        }
    }
#undef STG8
}

// ============ 128x512 GEMM with FUSED residual + LayerNorm epilogue ============
// (r15-proven: 3-buffer, 2-deep prefetch, counted vmcnt(5); see r15 comments.)
template <int OUT32>
__global__ __launch_bounds__(512, 2) void gemmN512(
    const ushort* __restrict__ A, const ushort* __restrict__ Bt,
    const float* __restrict__ bias, const ushort* __restrict__ res16,
    const float* __restrict__ gam, const float* __restrict__ bet,
    void* __restrict__ outp, int K) {
    extern __shared__ char smem[];  // 3 * 40960 (K-loop); epilogue reuses ~70KB
    const int t = threadIdx.x;
    const int w = t >> 6, l = t & 63;
    const int wr = w >> 2, wc = w & 3;
    const int nwg = gridDim.x, cpx = nwg >> 3;
    const int by = (blockIdx.x & 7) * cpx + (blockIdx.x >> 3);

    const int scoff = ((t & 3) ^ ((t >> 3) & 3)) * 8;
    const ushort* pA = A + (size_t)(by * 128 + (t >> 2)) * K + scoff;
    const ushort* pB = Bt + (size_t)(t >> 2) * K + scoff;
    const size_t u128K = (size_t)128 * K;

    const int Kt = K >> 5;  // BK=32

#define STG5(buf, kt)                                                          \
    {                                                                          \
        char* Lb = (buf) + (w << 10);                                          \
        gload16(pA + (kt) * 32, Lb);                                           \
        _Pragma("unroll")                                                      \
        for (int u = 0; u < 4; ++u)                                            \
            gload16(pB + (size_t)u * u128K + (kt) * 32, Lb + 8192 + u * 8192); \
    }

    const int Ra = wr * 64 + (l & 15);
    const int offA = Ra * 64 + (((l >> 4) ^ ((Ra >> 1) & 3)) << 4);
    const int Rb = wc * 128 + (l & 15);
    const int offB = 8192 + Rb * 64 + (((l >> 4) ^ ((Rb >> 1) & 3)) << 4);

    STG5(smem, 0);
    STG5(smem + 40960, 1);

    int b3 = 0;
    f32x4 acc[4][8] = {};
#pragma unroll 1
    for (int g = 0; g < Kt; ++g) {
        if (g + 1 < Kt) asm volatile("s_waitcnt vmcnt(5)" ::: "memory");
        else            asm volatile("s_waitcnt vmcnt(0)" ::: "memory");
        __builtin_amdgcn_s_barrier();
        __builtin_amdgcn_sched_barrier(0);

        const char* cb = smem + b3 * 40960;
        if (g + 2 < Kt) {
            int nb3 = b3 + 2; if (nb3 >= 3) nb3 -= 3;
            STG5(smem + nb3 * 40960, g + 2);
        }
        if (++b3 == 3) b3 = 0;

        bf16x8 a[4], b[8];
#pragma unroll
        for (int n = 0; n < 8; n++) b[n] = *(const bf16x8*)(cb + offB + n * 1024);
#pragma unroll
        for (int m = 0; m < 4; m++) a[m] = *(const bf16x8*)(cb + offA + m * 1024);
#pragma unroll
        for (int m = 0; m < 4; m++)
#pragma unroll
            for (int n = 0; n < 8; n++)
                acc[m][n] = __builtin_amdgcn_mfma_f32_16x16x32_bf16(a[m], b[n], acc[m][n], 0, 0, 0);
    }
#undef STG5

    const int row0 = wr * 64 + ((l >> 4) << 2);
    const int col0 = wc * 128 + (l & 15);
    float bv[8];
#pragma unroll
    for (int n = 0; n < 8; n++) bv[n] = bias[col0 + n * 16];
#pragma unroll
    for (int m = 0; m < 4; m++)
#pragma unroll
        for (int r = 0; r < 4; r++) {
            const int lrow = row0 + m * 16 + r;
            const size_t gbase = (size_t)(by * 128 + lrow) * 512 + col0;
#pragma unroll
            for (int n = 0; n < 8; n++)
                acc[m][n][r] += bv[n] + bf2f(res16[gbase + n * 16]);
        }

    __syncthreads();
    const int PST = 68;
    float* psum = (float*)smem;
    float* psq = (float*)(smem + 128 * PST * 4);
    float* stats = (float*)(smem + 2 * 128 * PST * 4);
    const int pcol = wc * 16 + (l & 15);
#pragma unroll
    for (int m = 0; m < 4; m++)
#pragma unroll
        for (int r = 0; r < 4; r++) {
            const int lrow = row0 + m * 16 + r;
            float s = 0.f, q = 0.f;
#pragma unroll
            for (int n = 0; n < 8; n++) {
                float v = acc[m][n][r];
                s += v; q += v * v;
            }
            psum[lrow * PST + pcol] = s;
            psq[lrow * PST + pcol] = q;
        }
    __syncthreads();
    {
        const int srow = t >> 2, sq4 = (t & 3) * 16;
        float s = 0.f, q = 0.f;
#pragma unroll
        for (int i = 0; i < 16; i++) {
            s += psum[srow * PST + sq4 + i];
            q += psq[srow * PST + sq4 + i];
        }
        s += __shfl_xor(s, 1, 64); q += __shfl_xor(q, 1, 64);
        s += __shfl_xor(s, 2, 64); q += __shfl_xor(q, 2, 64);
        if ((t & 3) == 0) {
            float mean = s * (1.f / 512.f);
            float var = q * (1.f / 512.f) - mean * mean;
            stats[srow * 2] = mean;
            stats[srow * 2 + 1] = rsqrtf(var + 1e-5f);
        }
    }
    __syncthreads();
    float gv[8], bev[8];
#pragma unroll
    for (int n = 0; n < 8; n++) { gv[n] = gam[col0 + n * 16]; bev[n] = bet[col0 + n * 16]; }
#pragma unroll
    for (int m = 0; m < 4; m++)
#pragma unroll
        for (int r = 0; r < 4; r++) {
            const int lrow = row0 + m * 16 + r;
            const float mean = stats[lrow * 2], rstd = stats[lrow * 2 + 1];
            const size_t gbase = (size_t)(by * 128 + lrow) * 512 + col0;
#pragma unroll
            for (int n = 0; n < 8; n++) {
                float o = (acc[m][n][r] - mean) * rstd * gv[n] + bev[n];
                if constexpr (OUT32) ((float*)outp)[gbase + n * 16] = o;
                else ((ushort*)outp)[gbase + n * 16] = f2bf(o);
            }
        }
}

// ---------------- kv partial reduction ----------------
__global__ __launch_bounds__(256) void kv_partial(
    const ushort* __restrict__ km, const ushort* __restrict__ v,
    float* __restrict__ kvp, float* __restrict__ ksump, int S) {
    __shared__ ushort kms[32 * 64];
    __shared__ ushort vs[32 * 64];
    const int t = threadIdx.x;
    const int bh = blockIdx.y, b = bh >> 3, h = bh & 7;
    const int d0 = (t >> 4) * 4, e0 = (t & 15) * 4;
    float acc[4][4] = {};
    float ks = 0.f;
    const int s_base = blockIdx.x * 512;
    const int r = t >> 3, c8 = (t & 7) * 8;
    for (int s0 = 0; s0 < 512; s0 += 32) {
        size_t grow = ((size_t)b * S + s_base + s0 + r) * 512 + h * 64 + c8;
        *(uint4*)&kms[r * 64 + c8] = *(const uint4*)&km[grow];
        *(uint4*)&vs[r * 64 + c8] = *(const uint4*)&v[grow];
        __syncthreads();
#pragma unroll 4
        for (int s = 0; s < 32; ++s) {
            ushort4 ka = *(const ushort4*)&kms[s * 64 + d0];
            ushort4 vb = *(const ushort4*)&vs[s * 64 + e0];
            float a0 = bf2f(ka.x), a1 = bf2f(ka.y), a2 = bf2f(ka.z), a3 = bf2f(ka.w);
            float b0 = bf2f(vb.x), b1 = bf2f(vb.y), b2 = bf2f(vb.z), b3 = bf2f(vb.w);
            acc[0][0] += a0 * b0; acc[0][1] += a0 * b1; acc[0][2] += a0 * b2; acc[0][3] += a0 * b3;
            acc[1][0] += a1 * b0; acc[1][1] += a1 * b1; acc[1][2] += a1 * b2; acc[1][3] += a1 * b3;
            acc[2][0] += a2 * b0; acc[2][1] += a2 * b1; acc[2][2] += a2 * b2; acc[2][3] += a2 * b3;
            acc[3][0] += a3 * b0; acc[3][1] += a3 * b1; acc[3][2] += a3 * b2; acc[3][3] += a3 * b3;
            if (t < 64) ks += bf2f(kms[s * 64 + t]);
        }
        __syncthreads();
    }
    float* dst = kvp + ((size_t)bh * 16 + blockIdx.x) * 4096;
#pragma unroll
    for (int i = 0; i < 4; i++)
#pragma unroll
        for (int j = 0; j < 4; j++)
            dst[(d0 + i) * 64 + e0 + j] = acc[i][j];
    if (t < 64) ksump[((size_t)bh * 16 + blockIdx.x) * 64 + t] = ks;
}

// reduce partials; kv emitted TRANSPOSED per head as bf16: kvt[bh][e][d]
__global__ void kv_reduce(const float* __restrict__ kvp, const float* __restrict__ ksump,
                          ushort* __restrict__ kvt, float* __restrict__ ksum) {
    int i = blockIdx.x * 256 + threadIdx.x;
    if (i < 32 * 4096) {
        int bh = i >> 12, de = i & 4095;
        int d = de >> 6, e = de & 63;
        float s = 0.f;
#pragma unroll
        for (int c = 0; c < 16; ++c) s += kvp[((size_t)bh * 16 + c) * 4096 + de];
        kvt[(size_t)bh * 4096 + e * 64 + d] = f2bf(s);
    } else {
        int j = i - 32 * 4096;
        if (j < 32 * 64) {
            int bh = j >> 6, d = j & 63;
            float s = 0.f;
#pragma unroll
            for (int c = 0; c < 16; ++c) s += ksump[((size_t)bh * 16 + c) * 64 + d];
            ksum[j] = s;
        }
    }
}

// ---------------- attn via MFMA: per (b,h) attn = qm[S,64] @ kv[64,64], * z ----------------
// r16 repack (fixed r17): frags -> LDS at padded stride 136 u16 (272B = 68 dwords
// == 4 mod 32 -> 2-way banks, free), then EXACT-coverage coalesced copy-out:
// 2 passes x (row = rr*64 + t>>2, 64B quarter q = t&3, 4x uint4) = 128 B/thread.
__global__ __launch_bounds__(256) void attn_mfma(
    const ushort* __restrict__ qm, const ushort* __restrict__ kvt,
    const float* __restrict__ ksum, ushort* __restrict__ attnE, int S) {
    __shared__ ushort pool[24576];  // As bytes [0,32768), Bs bytes [32768,49152)
    __shared__ float zbuf[128][2];
    __shared__ float ks2[128];
    const int t = threadIdx.x, w = t >> 6, l = t & 63;
    const int cx = blockIdx.x, by = blockIdx.y;
    const int b = (by * 128) / S;
    const int h0 = cx * 2;
    const size_t arow0 = (size_t)(by * 128) * 512 + cx * 128;

#pragma unroll
    for (int rd = 0; rd < 8; ++rd) {
        const ushort* g = qm + arow0 + (size_t)(rd * 16 + w * 4 + (l >> 4)) * 512 + (l & 15) * 8;
        gload16(g, (char*)pool + rd * 4096 + w * 1024);
    }
    const ushort* kvbase = kvt + (size_t)(b * 8 + h0) * 4096;
#pragma unroll
    for (int rd = 0; rd < 4; ++rd) {
        const ushort* g = kvbase + (rd * 32 + w * 8 + (l >> 3)) * 64 + (l & 7) * 8;
        gload16(g, (char*)pool + 32768 + rd * 4096 + w * 1024);
    }
    if (t < 128) ks2[t] = ksum[(b * 8 + h0) * 64 + t];
    __syncthreads();

    {
        const int r = t >> 1, hh = t & 1;
        float den = 0.f;
#pragma unroll
        for (int d0 = 0; d0 < 64; d0 += 8) {
            bf16x8 qv = *(const bf16x8*)&pool[r * 128 + hh * 64 + d0];
#pragma unroll
            for (int j = 0; j < 8; j++) den += bf2f((ushort)qv[j]) * ks2[hh * 64 + d0 + j];
        }
        zbuf[r][hh] = 1.0f / (den + 1e-6f);
    }

    const int wr = w >> 1, wc = w & 1;
    const int ar = wr * 64 + (l & 15);
    const int br = wc * 64 + (l & 15);
    const int ko = (l >> 4) * 8;
    f32x4 acc[4][4] = {};
#pragma unroll
    for (int ks_ = 0; ks_ < 2; ++ks_) {
        bf16x8 a[4], bb[4];
#pragma unroll
        for (int m = 0; m < 4; m++)
            a[m] = *(const bf16x8*)&pool[(ar + m * 16) * 128 + wc * 64 + ks_ * 32 + ko];
#pragma unroll
        for (int n = 0; n < 4; n++)
            bb[n] = *(const bf16x8*)&pool[16384 + (br + n * 16) * 64 + ks_ * 32 + ko];
#pragma unroll
        for (int m = 0; m < 4; m++)
#pragma unroll
            for (int n = 0; n < 4; n++)
                acc[m][n] = __builtin_amdgcn_mfma_f32_16x16x32_bf16(a[m], bb[n], acc[m][n], 0, 0, 0);
    }
    __syncthreads();  // zbuf ready AND all pool reads complete -> pool reusable

    // repack: frag (row rl, col wc*64+n*16+(l&15)) -> pool stride 136 u16
    const int row0l = wr * 64 + ((l >> 4) << 2);
#pragma unroll
    for (int n = 0; n < 4; n++)
#pragma unroll
        for (int m = 0; m < 4; m++)
#pragma unroll
            for (int r = 0; r < 4; r++) {
                const int rl = row0l + m * 16 + r;
                pool[rl * 136 + wc * 64 + n * 16 + (l & 15)] = f2bf(acc[m][n][r] * zbuf[rl][wc]);
            }
    __syncthreads();
    // exact-coverage coalesced copy-out: 128 rows x 256B; 2 passes, 4 threads/row,
    // 64B (4x uint4) per (row, quarter) -> 128 B/thread total.
#pragma unroll
    for (int rr = 0; rr < 2; ++rr) {
        const int row = rr * 64 + (t >> 2), q = t & 3;
        const uint4* srcp = (const uint4*)&pool[row * 136 + q * 32];
        uint4* dstp = (uint4*)&attnE[(size_t)(by * 128 + row) * 512 + cx * 128 + q * 32];
        dstp[0] = srcp[0];
        dstp[1] = srcp[1];
        // q*32 elements = 64B span? No: quarter is 32 u16 = 64 B = 4x uint4.
        dstp[2] = srcp[2];
        dstp[3] = srcp[3];
    }
}

extern "C" void kernel_launch(void* const* d_in, const int* in_sizes, int n_in,
                              void* d_out, int out_size, void* d_ws, size_t ws_size,
                              hipStream_t stream) {
    const int B = 4, S = 8192, E = 512, F = 2048;
    const int M = B * S;  // 32768
    const size_t SZ = (size_t)M * E * 2;  // 32 MiB
    const int SMEM = 131072;
    const int SMEMN = 122880;

    const float* src = (const float*)d_in[0];
    const float* Wq = (const float*)d_in[1];  const float* bq = (const float*)d_in[2];
    const float* Wk = (const float*)d_in[3];  const float* bk = (const float*)d_in[4];
    const float* Wv = (const float*)d_in[5];  const float* bv = (const float*)d_in[6];
    const float* Wo = (const float*)d_in[7];  const float* bo = (const float*)d_in[8];
    const float* W1 = (const float*)d_in[9];  const float* b1 = (const float*)d_in[10];
    const float* W2 = (const float*)d_in[11]; const float* b2 = (const float*)d_in[12];
    const float* g1 = (const float*)d_in[13]; const float* be1 = (const float*)d_in[14];
    const float* g2 = (const float*)d_in[15]; const float* be2 = (const float*)d_in[16];

    char* ws = (char*)d_ws;
    ushort* qm    = (ushort*)(ws + 0 * SZ);
    ushort* km    = (ushort*)(ws + 1 * SZ);
    ushort* v     = (ushort*)(ws + 2 * SZ);
    ushort* src16 = (ushort*)(ws + 3 * SZ);
    ushort* x16   = (ushort*)(ws + 4 * SZ);
    char*   tail  = ws + 6 * SZ;
    float*  kvp   = (float*)(tail);
    float*  ksump = (float*)(tail + 8388608);
    ushort* kvt   = (ushort*)(tail + 8519680);
    float*  ksum  = (float*)(tail + 8781824);
    float*  bqkv  = (float*)(tail + 8790016);
    ushort* wqkv  = (ushort*)(tail + 8796160);
    ushort* wot   = (ushort*)(tail + 10369024);
    ushort* w1t   = (ushort*)(tail + 10893312);
    ushort* w2t   = (ushort*)(tail + 12990464);
    ushort* attnE = km;
    ushort* hbuf  = (ushort*)(ws + 0);  // [M,F] bf16 = 128 MiB, spans 0..4*SZ

    hipFuncSetAttribute((const void*)gemm256<4, 3, 0>, hipFuncAttributeMaxDynamicSharedMemorySize, SMEM);
    hipFuncSetAttribute((const void*)gemm256<2, 2, 1>, hipFuncAttributeMaxDynamicSharedMemorySize, SMEM);
    hipFuncSetAttribute((const void*)gemmN512<0>, hipFuncAttributeMaxDynamicSharedMemorySize, SMEMN);
    hipFuncSetAttribute((const void*)gemmN512<1>, hipFuncAttributeMaxDynamicSharedMemorySize, SMEMN);

    // 1) merged prep
    prep<<<dim3(16384 + 3072 + 6), 256, 0, stream>>>(
        src, src16, Wq, Wk, Wv, Wo, W1, W2, wqkv, wot, w1t, w2t, bq, bk, bv, bqkv);

    // 2) fused QKV GEMM (N=1536, NT=3 over bx -> 256 blocks; elu+1 on q,k segments)
    gemm256<4, 3, 0><<<dim3(2 * 128), 512, SMEM, stream>>>(src16, wqkv, bqkv, nullptr, qm, M, 1536, E, 2);

    // 3) kv / ksum reduction
    kv_partial<<<dim3(16, 32), 256, 0, stream>>>(km, v, kvp, ksump, S);
    kv_reduce<<<dim3((32 * 4096 + 32 * 64 + 255) / 256), 256, 0, stream>>>(kvp, ksump, kvt, ksum);

    // 4) attention combine (MFMA, repacked coalesced stores)
    attn_mfma<<<dim3(4, M / 128), 256, 0, stream>>>(qm, kvt, ksum, attnE, S);

    // 5) output proj + residual + LN1 fused -> x16 (bf16)
    gemmN512<0><<<dim3(M / 128), 512, SMEMN, stream>>>(attnE, wot, bo, src16, g1, be1, x16, E);

    // 6) FFN: W1 (NT=2 over by -> 512 blocks), then W2 + residual + LN2 fused -> d_out (fp32)
    gemm256<2, 2, 1><<<dim3(8 * 64), 512, SMEM, stream>>>(x16, w1t, b1, nullptr, hbuf, M, F, E, 8);
    gemmN512<1><<<dim3(M / 128), 512, SMEMN, stream>>>(hbuf, w2t, b2, x16, g2, be2, (float*)d_out, F);
}

// Round 18
// 339.553 us; speedup vs baseline: 1.0186x; 1.0186x over previous
//
#include <hip/hip_runtime.h>
#include <hip/hip_bf16.h>

typedef __attribute__((ext_vector_type(8))) short bf16x8;
typedef __attribute__((ext_vector_type(4))) float f32x4;

__device__ inline ushort f2bf(float f) {
    uint u = __float_as_uint(f);
    u += 0x7fff + ((u >> 16) & 1);
    return (ushort)(u >> 16);
}
__device__ inline float bf2f(ushort h) {
    return __uint_as_float(((uint)h) << 16);
}

__device__ inline void gload16(const void* g, void* lds) {
    __builtin_amdgcn_global_load_lds(
        (const __attribute__((address_space(1))) void*)g,
        (__attribute__((address_space(3))) void*)lds, 16, 0, 0);
}

// ---------------- merged prep: src->bf16, 6 weight transpose-converts, bias concat ----------------
__global__ __launch_bounds__(256) void prep(
    const float* __restrict__ src, ushort* __restrict__ src16,
    const float* __restrict__ Wq, const float* __restrict__ Wk,
    const float* __restrict__ Wv, const float* __restrict__ Wo,
    const float* __restrict__ W1, const float* __restrict__ W2,
    ushort* __restrict__ wqkv, ushort* __restrict__ wot,
    ushort* __restrict__ w1t, ushort* __restrict__ w2t,
    const float* __restrict__ bq, const float* __restrict__ bk,
    const float* __restrict__ bv, float* __restrict__ bqkv) {
    __shared__ float tile[32][33];
    int bid = blockIdx.x;
    const int t = threadIdx.x;
    if (bid < 16384) {
        int i = bid * 256 + t;
        float4 a = ((const float4*)src)[i];
        ushort4 o;
        o.x = f2bf(a.x); o.y = f2bf(a.y); o.z = f2bf(a.z); o.w = f2bf(a.w);
        ((ushort4*)src16)[i] = o;
        return;
    }
    bid -= 16384;
    const float* in; ushort* out; int Kd, Nd;
    if (bid < 1024) {
        int m = bid >> 8;
        in = (m == 0) ? Wq : (m == 1) ? Wk : (m == 2) ? Wv : Wo;
        out = (m == 3) ? wot : (wqkv + m * 512 * 512);
        Kd = 512; Nd = 512; bid &= 255;
    } else if (bid < 2048) { in = W1; out = w1t; Kd = 512; Nd = 2048; bid -= 1024; }
    else if (bid < 3072) { in = W2; out = w2t; Kd = 2048; Nd = 512; bid -= 2048; }
    else {
        int i = (bid - 3072) * 256 + t;
        if (i < 512) bqkv[i] = bq[i];
        else if (i < 1024) bqkv[i] = bk[i - 512];
        else if (i < 1536) bqkv[i] = bv[i - 1024];
        return;
    }
    const int nx = Nd / 32;
    const int nbase = (bid % nx) * 32, kb = (bid / nx) * 32;
    const int tx = t & 31, ty = t >> 5;
#pragma unroll
    for (int i = 0; i < 4; i++)
        tile[ty + i * 8][tx] = in[(size_t)(kb + ty + i * 8) * Nd + nbase + tx];
    __syncthreads();
#pragma unroll
    for (int i = 0; i < 4; i++) {
        int n = nbase + ty + i * 8, k = kb + tx;
        out[(size_t)n * Kd + k] = f2bf(tile[tx][ty + i * 8]);
    }
}

// ============ 256x256 persistent GEMM: BK=64, 2x64KB dbuf, ONE barrier per K-tile ============
// (r12-proven; see round-12 comments for the full sync/WAR/swizzle argument.)
// EPI: 2 = relu bf16; 4 = fused QKV (seg<2: elu+1) -> [3][M][512]
template <int EPI, int NT, int GB>
__global__ __launch_bounds__(512, 2) void gemm256(
    const ushort* __restrict__ A, const ushort* __restrict__ Bt,
    const float* __restrict__ bias, const ushort* __restrict__ res16,
    ushort* __restrict__ out16, int M, int N, int K, int nb1) {
    extern __shared__ char smem[];  // 2 * 65536
    const int t = threadIdx.x;
    const int w = t >> 6, l = t & 63;
    const int wr = w >> 2, wc = w & 3;
    const int nwg = gridDim.x, cpx = nwg >> 3;
    const int swz = (blockIdx.x & 7) * cpx + (blockIdx.x >> 3);
    int bx0, by0;
    if (GB == 0) { bx0 = (swz % nb1) * NT; by0 = swz / nb1; }
    else         { bx0 = swz % nb1;        by0 = (swz / nb1) * NT; }

    const int scoff = ((t & 7) ^ ((t >> 3) & 7)) * 8;
    const ushort* pA = A + (size_t)(by0 * 256 + (t >> 3)) * K + scoff;
    const ushort* pB = Bt + (size_t)(bx0 * 256 + (t >> 3)) * K + scoff;
    const size_t u64K = (size_t)64 * K;

    const int Kt = K >> 6;  // BK=64
    const int TOT = NT * Kt;
    int skt = 0;
    size_t adv = 0;

#define STG8(buf)                                                              \
    {                                                                          \
        char* Lb = (buf) + (w << 10);                                          \
        _Pragma("unroll")                                                      \
        for (int u = 0; u < 4; ++u) {                                          \
            gload16(pA + (size_t)u * u64K + (GB ? adv : 0) + skt * 64,         \
                    Lb + u * 8192);                                            \
            gload16(pB + (size_t)u * u64K + (GB ? 0 : adv) + skt * 64,         \
                    Lb + 32768 + u * 8192);                                    \
        }                                                                      \
        if (++skt == Kt) { skt = 0; adv += (size_t)256 * K; }                  \
    }

    const int cA0 = ((l >> 4) ^ (l & 7)) * 16;
    const int cA1 = ((4 + (l >> 4)) ^ (l & 7)) * 16;
    const int baseA = (wr * 128 + (l & 15)) * 128;
    const int baseB = 32768 + (wc * 64 + (l & 15)) * 128;

    STG8(smem);

    f32x4 acc[8][4] = {};
    int g = 0;
    for (int j = 0; j < NT; ++j) {
#pragma unroll 1
        for (int kt = 0; kt < Kt; ++kt, ++g) {
            asm volatile("s_waitcnt vmcnt(0)" ::: "memory");
            __builtin_amdgcn_s_barrier();
            __builtin_amdgcn_sched_barrier(0);

            const char* cb = smem + (g & 1) * 65536;
            if (g + 1 < TOT) STG8(smem + ((g + 1) & 1) * 65536);

            bf16x8 a[8], b[4];
#pragma unroll
            for (int n = 0; n < 4; n++) b[n] = *(const bf16x8*)(cb + baseB + n * 2048 + cA0);
#pragma unroll
            for (int m = 0; m < 8; m++) a[m] = *(const bf16x8*)(cb + baseA + m * 2048 + cA0);
#pragma unroll
            for (int m = 0; m < 8; m++)
#pragma unroll
                for (int n = 0; n < 4; n++)
                    acc[m][n] = __builtin_amdgcn_mfma_f32_16x16x32_bf16(a[m], b[n], acc[m][n], 0, 0, 0);
#pragma unroll
            for (int n = 0; n < 4; n++) b[n] = *(const bf16x8*)(cb + baseB + n * 2048 + cA1);
#pragma unroll
            for (int m = 0; m < 8; m++) a[m] = *(const bf16x8*)(cb + baseA + m * 2048 + cA1);
#pragma unroll
            for (int m = 0; m < 8; m++)
#pragma unroll
                for (int n = 0; n < 4; n++)
                    acc[m][n] = __builtin_amdgcn_mfma_f32_16x16x32_bf16(a[m], b[n], acc[m][n], 0, 0, 0);
        }

        {
            const int bx = (GB == 0) ? (bx0 + j) : bx0;
            const int by = (GB == 0) ? by0 : (by0 + j);
            const int row0 = by * 256 + wr * 128 + ((l >> 4) << 2);
            const int col0 = bx * 256 + wc * 64 + (l & 15);
            const int seg = bx >> 1;
            const size_t segoff = (size_t)seg * M * 512;
            const int c511 = col0 & 511;
            float bv[4];
#pragma unroll
            for (int n = 0; n < 4; n++) bv[n] = bias[col0 + n * 16];
#pragma unroll
            for (int m = 0; m < 8; m++) {
#pragma unroll
                for (int r = 0; r < 4; r++) {
                    const int row = row0 + m * 16 + r;
                    const size_t base = (size_t)row * N + col0;
#pragma unroll
                    for (int n = 0; n < 4; n++) {
                        float vv = acc[m][n][r] + bv[n];
                        if constexpr (EPI == 2) {
                            vv = vv > 0.f ? vv : 0.f;
                            out16[base + n * 16] = f2bf(vv);
                        } else if constexpr (EPI == 4) {
                            if (seg < 2) vv = vv > 0.f ? vv + 1.f : __expf(vv);
                            out16[segoff + (size_t)row * 512 + c511 + n * 16] = f2bf(vv);
                        } else {
                            out16[base + n * 16] = f2bf(vv);
                        }
                    }
                }
            }
            if (j + 1 < NT) {
#pragma unroll
                for (int m = 0; m < 8; m++)
#pragma unroll
                    for (int n = 0; n < 4; n++)
                        acc[m][n] = (f32x4){0.f, 0.f, 0.f, 0.f};
            }
        }
    }
#undef STG8
}

// ============ 128x512 GEMM with FUSED residual + LayerNorm epilogue ============
// (r15-proven: 3-buffer, 2-deep prefetch, counted vmcnt(5); see r15 comments.)
template <int OUT32>
__global__ __launch_bounds__(512, 2) void gemmN512(
    const ushort* __restrict__ A, const ushort* __restrict__ Bt,
    const float* __restrict__ bias, const ushort* __restrict__ res16,
    const float* __restrict__ gam, const float* __restrict__ bet,
    void* __restrict__ outp, int K) {
    extern __shared__ char smem[];  // 3 * 40960 (K-loop); epilogue reuses ~70KB
    const int t = threadIdx.x;
    const int w = t >> 6, l = t & 63;
    const int wr = w >> 2, wc = w & 3;
    const int nwg = gridDim.x, cpx = nwg >> 3;
    const int by = (blockIdx.x & 7) * cpx + (blockIdx.x >> 3);

    const int scoff = ((t & 3) ^ ((t >> 3) & 3)) * 8;
    const ushort* pA = A + (size_t)(by * 128 + (t >> 2)) * K + scoff;
    const ushort* pB = Bt + (size_t)(t >> 2) * K + scoff;
    const size_t u128K = (size_t)128 * K;

    const int Kt = K >> 5;  // BK=32

#define STG5(buf, kt)                                                          \
    {                                                                          \
        char* Lb = (buf) + (w << 10);                                          \
        gload16(pA + (kt) * 32, Lb);                                           \
        _Pragma("unroll")                                                      \
        for (int u = 0; u < 4; ++u)                                            \
            gload16(pB + (size_t)u * u128K + (kt) * 32, Lb + 8192 + u * 8192); \
    }

    const int Ra = wr * 64 + (l & 15);
    const int offA = Ra * 64 + (((l >> 4) ^ ((Ra >> 1) & 3)) << 4);
    const int Rb = wc * 128 + (l & 15);
    const int offB = 8192 + Rb * 64 + (((l >> 4) ^ ((Rb >> 1) & 3)) << 4);

    STG5(smem, 0);
    STG5(smem + 40960, 1);

    int b3 = 0;
    f32x4 acc[4][8] = {};
#pragma unroll 1
    for (int g = 0; g < Kt; ++g) {
        if (g + 1 < Kt) asm volatile("s_waitcnt vmcnt(5)" ::: "memory");
        else            asm volatile("s_waitcnt vmcnt(0)" ::: "memory");
        __builtin_amdgcn_s_barrier();
        __builtin_amdgcn_sched_barrier(0);

        const char* cb = smem + b3 * 40960;
        if (g + 2 < Kt) {
            int nb3 = b3 + 2; if (nb3 >= 3) nb3 -= 3;
            STG5(smem + nb3 * 40960, g + 2);
        }
        if (++b3 == 3) b3 = 0;

        bf16x8 a[4], b[8];
#pragma unroll
        for (int n = 0; n < 8; n++) b[n] = *(const bf16x8*)(cb + offB + n * 1024);
#pragma unroll
        for (int m = 0; m < 4; m++) a[m] = *(const bf16x8*)(cb + offA + m * 1024);
#pragma unroll
        for (int m = 0; m < 4; m++)
#pragma unroll
            for (int n = 0; n < 8; n++)
                acc[m][n] = __builtin_amdgcn_mfma_f32_16x16x32_bf16(a[m], b[n], acc[m][n], 0, 0, 0);
    }
#undef STG5

    const int row0 = wr * 64 + ((l >> 4) << 2);
    const int col0 = wc * 128 + (l & 15);
    float bv[8];
#pragma unroll
    for (int n = 0; n < 8; n++) bv[n] = bias[col0 + n * 16];
#pragma unroll
    for (int m = 0; m < 4; m++)
#pragma unroll
        for (int r = 0; r < 4; r++) {
            const int lrow = row0 + m * 16 + r;
            const size_t gbase = (size_t)(by * 128 + lrow) * 512 + col0;
#pragma unroll
            for (int n = 0; n < 8; n++)
                acc[m][n][r] += bv[n] + bf2f(res16[gbase + n * 16]);
        }

    __syncthreads();
    const int PST = 68;
    float* psum = (float*)smem;
    float* psq = (float*)(smem + 128 * PST * 4);
    float* stats = (float*)(smem + 2 * 128 * PST * 4);
    const int pcol = wc * 16 + (l & 15);
#pragma unroll
    for (int m = 0; m < 4; m++)
#pragma unroll
        for (int r = 0; r < 4; r++) {
            const int lrow = row0 + m * 16 + r;
            float s = 0.f, q = 0.f;
#pragma unroll
            for (int n = 0; n < 8; n++) {
                float v = acc[m][n][r];
                s += v; q += v * v;
            }
            psum[lrow * PST + pcol] = s;
            psq[lrow * PST + pcol] = q;
        }
    __syncthreads();
    {
        const int srow = t >> 2, sq4 = (t & 3) * 16;
        float s = 0.f, q = 0.f;
#pragma unroll
        for (int i = 0; i < 16; i++) {
            s += psum[srow * PST + sq4 + i];
            q += psq[srow * PST + sq4 + i];
        }
        s += __shfl_xor(s, 1, 64); q += __shfl_xor(q, 1, 64);
        s += __shfl_xor(s, 2, 64); q += __shfl_xor(q, 2, 64);
        if ((t & 3) == 0) {
            float mean = s * (1.f / 512.f);
            float var = q * (1.f / 512.f) - mean * mean;
            stats[srow * 2] = mean;
            stats[srow * 2 + 1] = rsqrtf(var + 1e-5f);
        }
    }
    __syncthreads();
    float gv[8], bev[8];
#pragma unroll
    for (int n = 0; n < 8; n++) { gv[n] = gam[col0 + n * 16]; bev[n] = bet[col0 + n * 16]; }
#pragma unroll
    for (int m = 0; m < 4; m++)
#pragma unroll
        for (int r = 0; r < 4; r++) {
            const int lrow = row0 + m * 16 + r;
            const float mean = stats[lrow * 2], rstd = stats[lrow * 2 + 1];
            const size_t gbase = (size_t)(by * 128 + lrow) * 512 + col0;
#pragma unroll
            for (int n = 0; n < 8; n++) {
                float o = (acc[m][n][r] - mean) * rstd * gv[n] + bev[n];
                if constexpr (OUT32) ((float*)outp)[gbase + n * 16] = o;
                else ((ushort*)outp)[gbase + n * 16] = f2bf(o);
            }
        }
}

// ---------------- kv partial reduction ----------------
__global__ __launch_bounds__(256) void kv_partial(
    const ushort* __restrict__ km, const ushort* __restrict__ v,
    float* __restrict__ kvp, float* __restrict__ ksump, int S) {
    __shared__ ushort kms[32 * 64];
    __shared__ ushort vs[32 * 64];
    const int t = threadIdx.x;
    const int bh = blockIdx.y, b = bh >> 3, h = bh & 7;
    const int d0 = (t >> 4) * 4, e0 = (t & 15) * 4;
    float acc[4][4] = {};
    float ks = 0.f;
    const int s_base = blockIdx.x * 512;
    const int r = t >> 3, c8 = (t & 7) * 8;
    for (int s0 = 0; s0 < 512; s0 += 32) {
        size_t grow = ((size_t)b * S + s_base + s0 + r) * 512 + h * 64 + c8;
        *(uint4*)&kms[r * 64 + c8] = *(const uint4*)&km[grow];
        *(uint4*)&vs[r * 64 + c8] = *(const uint4*)&v[grow];
        __syncthreads();
#pragma unroll 4
        for (int s = 0; s < 32; ++s) {
            ushort4 ka = *(const ushort4*)&kms[s * 64 + d0];
            ushort4 vb = *(const ushort4*)&vs[s * 64 + e0];
            float a0 = bf2f(ka.x), a1 = bf2f(ka.y), a2 = bf2f(ka.z), a3 = bf2f(ka.w);
            float b0 = bf2f(vb.x), b1 = bf2f(vb.y), b2 = bf2f(vb.z), b3 = bf2f(vb.w);
            acc[0][0] += a0 * b0; acc[0][1] += a0 * b1; acc[0][2] += a0 * b2; acc[0][3] += a0 * b3;
            acc[1][0] += a1 * b0; acc[1][1] += a1 * b1; acc[1][2] += a1 * b2; acc[1][3] += a1 * b3;
            acc[2][0] += a2 * b0; acc[2][1] += a2 * b1; acc[2][2] += a2 * b2; acc[2][3] += a2 * b3;
            acc[3][0] += a3 * b0; acc[3][1] += a3 * b1; acc[3][2] += a3 * b2; acc[3][3] += a3 * b3;
            if (t < 64) ks += bf2f(kms[s * 64 + t]);
        }
        __syncthreads();
    }
    float* dst = kvp + ((size_t)bh * 16 + blockIdx.x) * 4096;
#pragma unroll
    for (int i = 0; i < 4; i++)
#pragma unroll
        for (int j = 0; j < 4; j++)
            dst[(d0 + i) * 64 + e0 + j] = acc[i][j];
    if (t < 64) ksump[((size_t)bh * 16 + blockIdx.x) * 64 + t] = ks;
}

// reduce partials; kv emitted TRANSPOSED per head as bf16: kvt[bh][e][d]
__global__ void kv_reduce(const float* __restrict__ kvp, const float* __restrict__ ksump,
                          ushort* __restrict__ kvt, float* __restrict__ ksum) {
    int i = blockIdx.x * 256 + threadIdx.x;
    if (i < 32 * 4096) {
        int bh = i >> 12, de = i & 4095;
        int d = de >> 6, e = de & 63;
        float s = 0.f;
#pragma unroll
        for (int c = 0; c < 16; ++c) s += kvp[((size_t)bh * 16 + c) * 4096 + de];
        kvt[(size_t)bh * 4096 + e * 64 + d] = f2bf(s);
    } else {
        int j = i - 32 * 4096;
        if (j < 32 * 64) {
            int bh = j >> 6, d = j & 63;
            float s = 0.f;
#pragma unroll
            for (int c = 0; c < 16; ++c) s += ksump[((size_t)bh * 16 + c) * 64 + d];
            ksum[j] = s;
        }
    }
}

// ---------------- attn via MFMA: per (b,h) attn = qm[S,64] @ kv[64,64], * z ----------------
__global__ __launch_bounds__(256) void attn_mfma(
    const ushort* __restrict__ qm, const ushort* __restrict__ kvt,
    const float* __restrict__ ksum, ushort* __restrict__ attnE, int S) {
    __shared__ ushort As[128 * 128];
    __shared__ ushort Bs[128 * 64];
    __shared__ float zbuf[128][2];
    __shared__ float ks2[128];
    const int t = threadIdx.x, w = t >> 6, l = t & 63;
    const int cx = blockIdx.x, by = blockIdx.y;
    const int b = (by * 128) / S;
    const int h0 = cx * 2;
    const size_t arow0 = (size_t)(by * 128) * 512 + cx * 128;

#pragma unroll
    for (int rd = 0; rd < 8; ++rd) {
        const ushort* g = qm + arow0 + (size_t)(rd * 16 + w * 4 + (l >> 4)) * 512 + (l & 15) * 8;
        gload16(g, (char*)As + rd * 4096 + w * 1024);
    }
    const ushort* kvbase = kvt + (size_t)(b * 8 + h0) * 4096;
#pragma unroll
    for (int rd = 0; rd < 4; ++rd) {
        const ushort* g = kvbase + (rd * 32 + w * 8 + (l >> 3)) * 64 + (l & 7) * 8;
        gload16(g, (char*)Bs + rd * 4096 + w * 1024);
    }
    if (t < 128) ks2[t] = ksum[(b * 8 + h0) * 64 + t];
    __syncthreads();

    {
        const int r = t >> 1, hh = t & 1;
        float den = 0.f;
#pragma unroll
        for (int d0 = 0; d0 < 64; d0 += 8) {
            bf16x8 qv = *(const bf16x8*)&As[r * 128 + hh * 64 + d0];
#pragma unroll
            for (int j = 0; j < 8; j++) den += bf2f((ushort)qv[j]) * ks2[hh * 64 + d0 + j];
        }
        zbuf[r][hh] = 1.0f / (den + 1e-6f);
    }

    const int wr = w >> 1, wc = w & 1;
    const int ar = wr * 64 + (l & 15);
    const int br = wc * 64 + (l & 15);
    const int ko = (l >> 4) * 8;
    f32x4 acc[4][4] = {};
#pragma unroll
    for (int ks_ = 0; ks_ < 2; ++ks_) {
        bf16x8 a[4], bb[4];
#pragma unroll
        for (int m = 0; m < 4; m++)
            a[m] = *(const bf16x8*)&As[(ar + m * 16) * 128 + wc * 64 + ks_ * 32 + ko];
#pragma unroll
        for (int n = 0; n < 4; n++)
            bb[n] = *(const bf16x8*)&Bs[(br + n * 16) * 64 + ks_ * 32 + ko];
#pragma unroll
        for (int m = 0; m < 4; m++)
#pragma unroll
            for (int n = 0; n < 4; n++)
                acc[m][n] = __builtin_amdgcn_mfma_f32_16x16x32_bf16(a[m], bb[n], acc[m][n], 0, 0, 0);
    }
    __syncthreads();

    const int row0l = wr * 64 + ((l >> 4) << 2);
    ushort* outbase = attnE + (size_t)(by * 128) * 512 + cx * 128;
#pragma unroll
    for (int n = 0; n < 4; n++) {
#pragma unroll
        for (int m = 0; m < 4; m++) {
#pragma unroll
            for (int r = 0; r < 4; r++) {
                int rl = row0l + m * 16 + r;
                float z = zbuf[rl][wc];
                outbase[(size_t)rl * 512 + wc * 64 + n * 16 + (l & 15)] = f2bf(acc[m][n][r] * z);
            }
        }
    }
}

extern "C" void kernel_launch(void* const* d_in, const int* in_sizes, int n_in,
                              void* d_out, int out_size, void* d_ws, size_t ws_size,
                              hipStream_t stream) {
    const int B = 4, S = 8192, E = 512, F = 2048;
    const int M = B * S;  // 32768
    const size_t SZ = (size_t)M * E * 2;  // 32 MiB
    const int SMEM = 131072;
    const int SMEMN = 122880;

    const float* src = (const float*)d_in[0];
    const float* Wq = (const float*)d_in[1];  const float* bq = (const float*)d_in[2];
    const float* Wk = (const float*)d_in[3];  const float* bk = (const float*)d_in[4];
    const float* Wv = (const float*)d_in[5];  const float* bv = (const float*)d_in[6];
    const float* Wo = (const float*)d_in[7];  const float* bo = (const float*)d_in[8];
    const float* W1 = (const float*)d_in[9];  const float* b1 = (const float*)d_in[10];
    const float* W2 = (const float*)d_in[11]; const float* b2 = (const float*)d_in[12];
    const float* g1 = (const float*)d_in[13]; const float* be1 = (const float*)d_in[14];
    const float* g2 = (const float*)d_in[15]; const float* be2 = (const float*)d_in[16];

    char* ws = (char*)d_ws;
    ushort* qm    = (ushort*)(ws + 0 * SZ);
    ushort* km    = (ushort*)(ws + 1 * SZ);
    ushort* v     = (ushort*)(ws + 2 * SZ);
    ushort* src16 = (ushort*)(ws + 3 * SZ);
    ushort* x16   = (ushort*)(ws + 4 * SZ);
    char*   tail  = ws + 6 * SZ;
    float*  kvp   = (float*)(tail);
    float*  ksump = (float*)(tail + 8388608);
    ushort* kvt   = (ushort*)(tail + 8519680);
    float*  ksum  = (float*)(tail + 8781824);
    float*  bqkv  = (float*)(tail + 8790016);
    ushort* wqkv  = (ushort*)(tail + 8796160);
    ushort* wot   = (ushort*)(tail + 10369024);
    ushort* w1t   = (ushort*)(tail + 10893312);
    ushort* w2t   = (ushort*)(tail + 12990464);
    ushort* attnE = km;
    ushort* hbuf  = (ushort*)(ws + 0);  // [M,F] bf16 = 128 MiB, spans 0..4*SZ

    hipFuncSetAttribute((const void*)gemm256<4, 3, 0>, hipFuncAttributeMaxDynamicSharedMemorySize, SMEM);
    hipFuncSetAttribute((const void*)gemm256<2, 4, 1>, hipFuncAttributeMaxDynamicSharedMemorySize, SMEM);
    hipFuncSetAttribute((const void*)gemmN512<0>, hipFuncAttributeMaxDynamicSharedMemorySize, SMEMN);
    hipFuncSetAttribute((const void*)gemmN512<1>, hipFuncAttributeMaxDynamicSharedMemorySize, SMEMN);

    // 1) merged prep
    prep<<<dim3(16384 + 3072 + 6), 256, 0, stream>>>(
        src, src16, Wq, Wk, Wv, Wo, W1, W2, wqkv, wot, w1t, w2t, bq, bk, bv, bqkv);

    // 2) fused QKV GEMM (N=1536, NT=3 over bx -> 256 blocks; elu+1 on q,k segments)
    gemm256<4, 3, 0><<<dim3(2 * 128), 512, SMEM, stream>>>(src16, wqkv, bqkv, nullptr, qm, M, 1536, E, 2);

    // 3) kv / ksum reduction
    kv_partial<<<dim3(16, 32), 256, 0, stream>>>(km, v, kvp, ksump, S);
    kv_reduce<<<dim3((32 * 4096 + 32 * 64 + 255) / 256), 256, 0, stream>>>(kvp, ksump, kvt, ksum);

    // 4) attention combine (MFMA)
    attn_mfma<<<dim3(4, M / 128), 256, 0, stream>>>(qm, kvt, ksum, attnE, S);

    // 5) output proj + residual + LN1 fused -> x16 (bf16)
    gemmN512<0><<<dim3(M / 128), 512, SMEMN, stream>>>(attnE, wot, bo, src16, g1, be1, x16, E);

    // 6) FFN: W1 (NT=4 over by -> 256 blocks, A streamed once), then W2 + residual + LN2 fused -> d_out (fp32)
    gemm256<2, 4, 1><<<dim3(8 * 32), 512, SMEM, stream>>>(x16, w1t, b1, nullptr, hbuf, M, F, E, 8);
    gemmN512<1><<<dim3(M / 128), 512, SMEMN, stream>>>(hbuf, w2t, b2, x16, g2, be2, (float*)d_out, F);
}